// Round 3
// baseline (119.029 us; speedup 1.0000x reference)
//
#include <hip/hip_runtime.h>
#include <math.h>

#define B_ 32
#define T_ 512
#define D_ 256
#define TP_ 514              // padded T: one zero row each side
#define KTOT 768             // 3 taps x 256 channels
#define NSTEP 24             // KTOT / 32
#define TILE_M 64

typedef __bf16 bf16x8 __attribute__((ext_vector_type(8)));
typedef float  f32x4  __attribute__((ext_vector_type(4)));

// ---------------------------------------------------------------------------
// Conv layer 1 as a barrier-free register GEMM + fused bias/ReLU/LayerNorm.
// 512 threads = 8 waves; wave owns cols [wid*32, wid*32+32), all 64 rows.
// A and B fragments are loaded straight from global (no LDS): each wave-load
// touches 16 distinct rows at 16B/lane covering full 64B lines (L1/L2-hot).
//   a[mf][lane] = xpad[(bb*TP+t0+tap + mf*16+p)*256 + (t&7)*32 + q*8 ..]
//   b[nf][lane] = bmat[(wid*32+nf*16+p)*768 + t*32 + q*8 ..]
// ---------------------------------------------------------------------------
__global__ __launch_bounds__(512) void gemm1_ln_kernel(
    const __bf16* __restrict__ xpad,   // (B, 514, 256)
    const __bf16* __restrict__ bmat,   // (256, 768)
    const float* __restrict__ bias,
    const float* __restrict__ gamma,
    const float* __restrict__ beta,
    __bf16* __restrict__ dst)          // padded (B,514,256)
{
    __shared__ float part[64 * 8 * 2];
    __shared__ float tot[64 * 2];
    const int tid = threadIdx.x, lane = tid & 63, wid = tid >> 6;
    const int p = lane & 15, q = lane >> 4;
    const int m0 = blockIdx.x * TILE_M;
    const int bb = m0 >> 9, t0 = m0 & 511;

    const __bf16* aBase = xpad + ((size_t)bb * TP_ + t0 + p) * D_ + q * 8;
    const __bf16* bBase = bmat + (size_t)(wid * 32 + p) * KTOT + q * 8;

    f32x4 acc[4][2];
#pragma unroll
    for (int mf = 0; mf < 4; ++mf)
#pragma unroll
        for (int nf = 0; nf < 2; ++nf)
            acc[mf][nf] = (f32x4){0.f, 0.f, 0.f, 0.f};

    bf16x8 A0[4], A1[4], B0[2], B1[2];
    auto LOADA = [&](bf16x8 (&A)[4], int t) {
        const int off = (t >> 3) * D_ + (t & 7) * 32;
#pragma unroll
        for (int mf = 0; mf < 4; ++mf)
            A[mf] = *(const bf16x8*)(aBase + (size_t)mf * 16 * D_ + off);
    };
    auto LOADB = [&](bf16x8 (&Bv)[2], int t) {
#pragma unroll
        for (int nf = 0; nf < 2; ++nf)
            Bv[nf] = *(const bf16x8*)(bBase + (size_t)nf * 16 * KTOT + t * 32);
    };
    auto MM = [&](bf16x8 (&A)[4], bf16x8 (&Bv)[2]) {
#pragma unroll
        for (int mf = 0; mf < 4; ++mf)
#pragma unroll
            for (int nf = 0; nf < 2; ++nf)
                acc[mf][nf] = __builtin_amdgcn_mfma_f32_16x16x32_bf16(
                    A[mf], Bv[nf], acc[mf][nf], 0, 0, 0);
    };

    LOADA(A0, 0); LOADB(B0, 0);
#pragma unroll
    for (int t2 = 0; t2 < 12; ++t2) {
        LOADA(A1, 2 * t2 + 1); LOADB(B1, 2 * t2 + 1);
        MM(A0, B0);
        if (2 * t2 + 2 < NSTEP) { LOADA(A0, 2 * t2 + 2); LOADB(B0, 2 * t2 + 2); }
        MM(A1, B1);
    }

    // ---- epilogue: bias+ReLU partials -> cross-wave LN -> bf16 store ----
    float bcol[2], gcol[2], becol[2];
#pragma unroll
    for (int nf = 0; nf < 2; ++nf) {
        int c = wid * 32 + nf * 16 + p;
        bcol[nf] = bias[c]; gcol[nf] = gamma[c]; becol[nf] = beta[c];
    }
#pragma unroll
    for (int mf = 0; mf < 4; ++mf)
#pragma unroll
        for (int r = 0; r < 4; ++r) {
            float s = 0.f, s2 = 0.f;
#pragma unroll
            for (int nf = 0; nf < 2; ++nf) {
                float y = fmaxf(acc[mf][nf][r] + bcol[nf], 0.f);
                s += y; s2 += y * y;
            }
            s  += __shfl_xor(s, 1);  s  += __shfl_xor(s, 2);
            s  += __shfl_xor(s, 4);  s  += __shfl_xor(s, 8);
            s2 += __shfl_xor(s2, 1); s2 += __shfl_xor(s2, 2);
            s2 += __shfl_xor(s2, 4); s2 += __shfl_xor(s2, 8);
            if (p == 0) {
                int row = mf * 16 + q * 4 + r;
                part[(row * 8 + wid) * 2]     = s;
                part[(row * 8 + wid) * 2 + 1] = s2;
            }
        }
    __syncthreads();
    if (tid < 64) {
        float s = 0.f, s2 = 0.f;
#pragma unroll
        for (int w = 0; w < 8; ++w) {
            s  += part[(tid * 8 + w) * 2];
            s2 += part[(tid * 8 + w) * 2 + 1];
        }
        float m = s * (1.f / 256.f);
        float v = s2 * (1.f / 256.f) - m * m;
        tot[tid * 2]     = m;
        tot[tid * 2 + 1] = rsqrtf(v + 1e-5f);
    }
    __syncthreads();
#pragma unroll
    for (int mf = 0; mf < 4; ++mf)
#pragma unroll
        for (int r = 0; r < 4; ++r) {
            int row = mf * 16 + q * 4 + r;
            float m  = tot[row * 2];
            float rs = tot[row * 2 + 1];
            size_t gb = ((size_t)bb * TP_ + 1 + t0 + row) * D_;
#pragma unroll
            for (int nf = 0; nf < 2; ++nf) {
                int c = wid * 32 + nf * 16 + p;
                float y = fmaxf(acc[mf][nf][r] + bcol[nf], 0.f);
                dst[gb + c] = (__bf16)((y - m) * rs * gcol[nf] + becol[nf]);
            }
        }
}

// ---------------------------------------------------------------------------
// Conv layer 2, same core, but the LayerNorm + (h @ wl + bl) linear are folded
// into the epilogue:  pred[row] = rstd*(S3 - mean*Sgw) + Sbw, with
// S3 = sum_c y*g*wl, Sgw = sum_c g*wl, Sbw = sum_c be*wl.  Only pred written.
// ---------------------------------------------------------------------------
__global__ __launch_bounds__(512) void gemm2_pred_kernel(
    const __bf16* __restrict__ h1pad,  // (B, 514, 256)
    const __bf16* __restrict__ bmat,
    const float* __restrict__ bias,
    const float* __restrict__ gamma,
    const float* __restrict__ beta,
    const float* __restrict__ wl,
    const float* __restrict__ bl,
    float* __restrict__ pred)          // (B, T)
{
    __shared__ float part[64 * 8 * 4];  // s, s2, s3, pad
    __shared__ float sg[2];
    const int tid = threadIdx.x, lane = tid & 63, wid = tid >> 6;
    const int p = lane & 15, q = lane >> 4;
    const int m0 = blockIdx.x * TILE_M;
    const int bb = m0 >> 9, t0 = m0 & 511;

    if (wid == 0) {   // Sgw, Sbw: 64-lane reduction over 256 channels
        f32x4 g  = *(const f32x4*)(gamma + 4 * lane);
        f32x4 be = *(const f32x4*)(beta  + 4 * lane);
        f32x4 w  = *(const f32x4*)(wl    + 4 * lane);
        float a = g[0]*w[0] + g[1]*w[1] + g[2]*w[2] + g[3]*w[3];
        float b = be[0]*w[0] + be[1]*w[1] + be[2]*w[2] + be[3]*w[3];
#pragma unroll
        for (int off = 32; off >= 1; off >>= 1) {
            a += __shfl_xor(a, off); b += __shfl_xor(b, off);
        }
        if (lane == 0) { sg[0] = a; sg[1] = b + bl[0]; }
    }

    const __bf16* aBase = h1pad + ((size_t)bb * TP_ + t0 + p) * D_ + q * 8;
    const __bf16* bBase = bmat + (size_t)(wid * 32 + p) * KTOT + q * 8;

    f32x4 acc[4][2];
#pragma unroll
    for (int mf = 0; mf < 4; ++mf)
#pragma unroll
        for (int nf = 0; nf < 2; ++nf)
            acc[mf][nf] = (f32x4){0.f, 0.f, 0.f, 0.f};

    bf16x8 A0[4], A1[4], B0[2], B1[2];
    auto LOADA = [&](bf16x8 (&A)[4], int t) {
        const int off = (t >> 3) * D_ + (t & 7) * 32;
#pragma unroll
        for (int mf = 0; mf < 4; ++mf)
            A[mf] = *(const bf16x8*)(aBase + (size_t)mf * 16 * D_ + off);
    };
    auto LOADB = [&](bf16x8 (&Bv)[2], int t) {
#pragma unroll
        for (int nf = 0; nf < 2; ++nf)
            Bv[nf] = *(const bf16x8*)(bBase + (size_t)nf * 16 * KTOT + t * 32);
    };
    auto MM = [&](bf16x8 (&A)[4], bf16x8 (&Bv)[2]) {
#pragma unroll
        for (int mf = 0; mf < 4; ++mf)
#pragma unroll
            for (int nf = 0; nf < 2; ++nf)
                acc[mf][nf] = __builtin_amdgcn_mfma_f32_16x16x32_bf16(
                    A[mf], Bv[nf], acc[mf][nf], 0, 0, 0);
    };

    LOADA(A0, 0); LOADB(B0, 0);
#pragma unroll
    for (int t2 = 0; t2 < 12; ++t2) {
        LOADA(A1, 2 * t2 + 1); LOADB(B1, 2 * t2 + 1);
        MM(A0, B0);
        if (2 * t2 + 2 < NSTEP) { LOADA(A0, 2 * t2 + 2); LOADB(B0, 2 * t2 + 2); }
        MM(A1, B1);
    }

    float bcol[2], gwcol[2];
#pragma unroll
    for (int nf = 0; nf < 2; ++nf) {
        int c = wid * 32 + nf * 16 + p;
        bcol[nf]  = bias[c];
        gwcol[nf] = gamma[c] * wl[c];
    }
#pragma unroll
    for (int mf = 0; mf < 4; ++mf)
#pragma unroll
        for (int r = 0; r < 4; ++r) {
            float s = 0.f, s2 = 0.f, s3 = 0.f;
#pragma unroll
            for (int nf = 0; nf < 2; ++nf) {
                float y = fmaxf(acc[mf][nf][r] + bcol[nf], 0.f);
                s += y; s2 += y * y; s3 += y * gwcol[nf];
            }
#pragma unroll
            for (int off = 8; off >= 1; off >>= 1) {
                s  += __shfl_xor(s, off);
                s2 += __shfl_xor(s2, off);
                s3 += __shfl_xor(s3, off);
            }
            if (p == 0) {
                int row = mf * 16 + q * 4 + r;
                part[(row * 8 + wid) * 4]     = s;
                part[(row * 8 + wid) * 4 + 1] = s2;
                part[(row * 8 + wid) * 4 + 2] = s3;
            }
        }
    __syncthreads();
    if (tid < 64) {
        float s = 0.f, s2 = 0.f, s3 = 0.f;
#pragma unroll
        for (int w = 0; w < 8; ++w) {
            s  += part[(tid * 8 + w) * 4];
            s2 += part[(tid * 8 + w) * 4 + 1];
            s3 += part[(tid * 8 + w) * 4 + 2];
        }
        float m  = s * (1.f / 256.f);
        float v  = s2 * (1.f / 256.f) - m * m;
        float rs = rsqrtf(v + 1e-5f);
        pred[bb * T_ + t0 + tid] = rs * (s3 - m * sg[0]) + sg[1];
    }
}

// xpad (zero-padded bf16 x), BmatT for both convs, zero pad rows of h1pad.
__global__ __launch_bounds__(256) void prep_kernel(
    const float* __restrict__ x, const float* __restrict__ w1,
    const float* __restrict__ w2,
    __bf16* __restrict__ xpad, __bf16* __restrict__ bm1,
    __bf16* __restrict__ bm2, __bf16* __restrict__ h1pad)
{
    const int NX = B_ * TP_ * D_;
    const int NW = D_ * KTOT;
    const int NZ = B_ * 2 * D_;
    const int total = NX + 2 * NW + NZ;
    for (int idx = blockIdx.x * blockDim.x + threadIdx.x; idx < total;
         idx += gridDim.x * blockDim.x) {
        if (idx < NX) {
            int b = idx / (TP_ * D_);
            int rem = idx - b * (TP_ * D_);
            int r = rem >> 8, d = rem & 255;
            int t = r - 1;
            float v = ((unsigned)t < (unsigned)T_) ? x[((size_t)b * T_ + t) * D_ + d] : 0.f;
            xpad[idx] = (__bf16)v;
        } else if (idx < NX + 2 * NW) {
            int j = idx - NX;
            const float* ws = w1;
            __bf16* bm = bm1;
            if (j >= NW) { j -= NW; ws = w2; bm = bm2; }
            int n = j / KTOT;
            int kap = j - n * KTOT;
            int k = kap >> 8, i = kap & 255;
            bm[j] = (__bf16)ws[(n * D_ + i) * 3 + k];
        } else {
            int j = idx - NX - 2 * NW;
            int b = j >> 9, qq = (j >> 8) & 1, d = j & 255;
            h1pad[((size_t)b * TP_ + (qq ? TP_ - 1 : 0)) * D_ + d] = (__bf16)0.f;
        }
    }
}

// Per-batch inclusive cumsum of durations (ALPHA=1.0 -> dur == target).
__global__ __launch_bounds__(512) void scan_kernel(
    const int* __restrict__ td, int* __restrict__ ends)
{
    __shared__ int s[T_];
    int b = blockIdx.x, t = threadIdx.x;
    s[t] = td[b * T_ + t];
    __syncthreads();
    for (int off = 1; off < T_; off <<= 1) {
        int add = (t >= off) ? s[t - off] : 0;
        __syncthreads();
        s[t] += add;
        __syncthreads();
    }
    ends[b * T_ + t] = s[t];
}

// out[b,m,:] = x[b, t(m), :] via binary search over ends; zeros past lens[b].
__global__ __launch_bounds__(256) void gather_kernel(
    const float* __restrict__ x, const int* __restrict__ ends,
    float* __restrict__ out, int maxLen)
{
    int tid = threadIdx.x, wd = tid >> 6, lane = tid & 63;
    int idx = blockIdx.x * 4 + wd;
    int b = idx / maxLen, m = idx % maxLen;
    if (b >= B_) return;
    const int* e = &ends[b * T_];
    float4 r = make_float4(0.f, 0.f, 0.f, 0.f);
    if (m < e[T_ - 1]) {
        int lo = 0, hi = T_ - 1;   // first t with ends[t] > m
        while (lo < hi) {
            int mid = (lo + hi) >> 1;
            if (e[mid] > m) hi = mid; else lo = mid + 1;
        }
        r = *(const float4*)(&x[((size_t)b * T_ + lo) * D_ + 4 * lane]);
    }
    *(float4*)(&out[((size_t)b * maxLen + m) * D_ + 4 * lane]) = r;
}

extern "C" void kernel_launch(void* const* d_in, const int* in_sizes, int n_in,
                              void* d_out, int out_size, void* d_ws, size_t ws_size,
                              hipStream_t stream) {
    const float* x   = (const float*)d_in[0];
    const int*   td  = (const int*)d_in[1];
    const float* w1  = (const float*)d_in[2];
    const float* b1  = (const float*)d_in[3];
    const float* g1  = (const float*)d_in[4];
    const float* be1 = (const float*)d_in[5];
    const float* w2  = (const float*)d_in[6];
    const float* b2  = (const float*)d_in[7];
    const float* g2  = (const float*)d_in[8];
    const float* be2 = (const float*)d_in[9];
    const float* wl  = (const float*)d_in[10];
    const float* bl  = (const float*)d_in[11];
    float* outp = (float*)d_out;

    const int BT = B_ * T_;
    const int maxLen = (out_size - BT) / (B_ * D_);
    float* predp = outp + (size_t)B_ * maxLen * D_;

    const size_t SZ_XPAD = (size_t)B_ * TP_ * D_ * 2;
    const size_t SZ_H1   = SZ_XPAD;
    const size_t SZ_BM   = (size_t)D_ * KTOT * 2;
    const size_t SZ_ENDS = 65536;
    const size_t need = SZ_ENDS + SZ_XPAD + SZ_H1 + 2 * SZ_BM;

    int* endsp = (int*)d_ws;
    char* base;
    if (ws_size >= need) base = (char*)d_ws + SZ_ENDS;
    else                 base = (char*)d_out;   // consumed before gather overwrites

    __bf16* xpadp  = (__bf16*)(base);
    __bf16* h1padp = (__bf16*)(base + SZ_XPAD);
    __bf16* bm1p   = (__bf16*)(base + SZ_XPAD + SZ_H1);
    __bf16* bm2p   = (__bf16*)(base + SZ_XPAD + SZ_H1 + SZ_BM);

    prep_kernel<<<2048, 256, 0, stream>>>(x, w1, w2, xpadp, bm1p, bm2p, h1padp);
    gemm1_ln_kernel<<<BT / TILE_M, 512, 0, stream>>>(xpadp, bm1p, b1, g1, be1, h1padp);
    gemm2_pred_kernel<<<BT / TILE_M, 512, 0, stream>>>(h1padp, bm2p, b2, g2, be2, wl, bl, predp);
    scan_kernel<<<B_, T_, 0, stream>>>(td, endsp);
    gather_kernel<<<(B_ * maxLen + 3) / 4, 256, 0, stream>>>(x, endsp, outp, maxLen);
}

// Round 4
// 79.467 us; speedup vs baseline: 1.4978x; 1.4978x over previous
//
#include <hip/hip_runtime.h>
#include <math.h>

#define B_ 32
#define T_ 512
#define D_ 256
#define TP_ 514              // padded T: one zero row each side
#define KTOT 768             // 3 taps x 256 channels
#define NSTEP 24             // KTOT / 32
#define TILE_M 64

typedef __bf16 bf16x8 __attribute__((ext_vector_type(8)));
typedef float  f32x4  __attribute__((ext_vector_type(4)));

__device__ __forceinline__ void gload16(const void* g, void* l) {
    __builtin_amdgcn_global_load_lds(
        (const __attribute__((address_space(1))) unsigned int*)g,
        (__attribute__((address_space(3))) unsigned int*)l, 16, 0, 0);
}

// Ring-3 LDS pipeline, 2 stages in flight, counted vmcnt (T3/T4 recipe).
// 256 threads / 4 waves; wave computes 64 rows x 64 cols (acc 4x4).
// Per stage per thread: 1 A-chunk + 4 B-chunks = 5 global_load_lds (uniform).
// XOR swizzle (chunk ^= row&3) on BOTH the gload source and ds_read side.
#define BUFSZ 20480   // A 4KB + B 16KB

#define PIPE_BODY(T, CBUF, SBUF, DOSTAGE, LAST)                         \
    do {                                                                \
        if (LAST) asm volatile("s_waitcnt vmcnt(0)" ::: "memory");      \
        else      asm volatile("s_waitcnt vmcnt(5)" ::: "memory");      \
        __builtin_amdgcn_s_barrier();                                   \
        if (DOSTAGE) STAGE((T) + 2, SBUF);                              \
        COMPUTE(CBUF);                                                  \
    } while (0)

#define GEMM_CORE(ASRC)                                                  \
    const int tid = threadIdx.x, lane = tid & 63, wid = tid >> 6;        \
    const int p = lane & 15, q = lane >> 4;                              \
    const int m0 = blockIdx.x * TILE_M;                                  \
    const int bb = m0 >> 9, t0 = m0 & 511;                               \
    const __bf16* aBase = (ASRC) + ((size_t)bb * TP_ + t0) * D_;         \
    f32x4 acc[4][4];                                                     \
    _Pragma("unroll")                                                    \
    for (int mf = 0; mf < 4; ++mf)                                       \
        _Pragma("unroll")                                                \
        for (int nf = 0; nf < 4; ++nf)                                   \
            acc[mf][nf] = (f32x4){0.f, 0.f, 0.f, 0.f};                   \
    auto STAGE = [&](int kstep, int buf) {                               \
        unsigned char* Ab = ring + buf * BUFSZ;                          \
        {   /* A: 64 rows x 32 bf16, chunk = tid */                      \
            int r = tid >> 2, cb = tid & 3, scb = cb ^ (r & 3);          \
            int k = kstep >> 3, i0 = (kstep & 7) * 32;                   \
            gload16(aBase + (size_t)(r + k) * D_ + i0 + scb * 8,         \
                    Ab + tid * 16);                                      \
        }                                                                \
        _Pragma("unroll")                                                \
        for (int pp = 0; pp < 4; ++pp) {  /* B: 256 rows x 32 bf16 */    \
            int c = pp * 256 + tid;                                      \
            int n = c >> 2, cb = c & 3, scb = cb ^ (n & 3);              \
            gload16(bmat + (size_t)n * KTOT + kstep * 32 + scb * 8,      \
                    Ab + 4096 + c * 16);                                 \
        }                                                                \
    };                                                                   \
    auto COMPUTE = [&](int buf) {                                        \
        unsigned char* Ab = ring + buf * BUFSZ;                          \
        unsigned char* Bb = Ab + 4096;                                   \
        const int swz = ((lane >> 4) ^ (lane & 3)) * 16;                 \
        const int rA = lane & 15;                                        \
        bf16x8 a[4], bv[4];                                              \
        _Pragma("unroll")                                                \
        for (int mf = 0; mf < 4; ++mf)                                   \
            a[mf] = *(const bf16x8*)(Ab + (mf * 16 + rA) * 64 + swz);    \
        _Pragma("unroll")                                                \
        for (int nf = 0; nf < 4; ++nf)                                   \
            bv[nf] = *(const bf16x8*)(Bb + (wid * 64 + nf * 16 + rA) * 64 + swz); \
        _Pragma("unroll")                                                \
        for (int mf = 0; mf < 4; ++mf)                                   \
            _Pragma("unroll")                                            \
            for (int nf = 0; nf < 4; ++nf)                               \
                acc[mf][nf] = __builtin_amdgcn_mfma_f32_16x16x32_bf16(   \
                    a[mf], bv[nf], acc[mf][nf], 0, 0, 0);                \
    };                                                                   \
    STAGE(0, 0); STAGE(1, 1);                                            \
    for (int t2 = 0; t2 < 7; ++t2) {                                     \
        int t = 3 * t2;                                                  \
        PIPE_BODY(t,     0, 2, true, false);                             \
        PIPE_BODY(t + 1, 1, 0, true, false);                             \
        PIPE_BODY(t + 2, 2, 1, true, false);                             \
    }                                                                    \
    PIPE_BODY(21, 0, 2, true,  false);                                   \
    PIPE_BODY(22, 1, 0, false, false);                                   \
    PIPE_BODY(23, 2, 1, false, true);

// ---------------- conv1: GEMM + bias/ReLU/LayerNorm -> bf16 h1pad ----------
__global__ __launch_bounds__(256) void gemm1_ln_kernel(
    const __bf16* __restrict__ xpad,   // (B, 514, 256)
    const __bf16* __restrict__ bmat,   // (256, 768)
    const float* __restrict__ bias,
    const float* __restrict__ gamma,
    const float* __restrict__ beta,
    __bf16* __restrict__ dst)          // padded (B,514,256)
{
    __shared__ __align__(16) unsigned char ring[3 * BUFSZ];
    __shared__ float part[64 * 4 * 2];
    __shared__ float tot[64 * 2];
    GEMM_CORE(xpad)

    float bcol[4], gcol[4], becol[4];
#pragma unroll
    for (int nf = 0; nf < 4; ++nf) {
        int c = wid * 64 + nf * 16 + p;
        bcol[nf] = bias[c]; gcol[nf] = gamma[c]; becol[nf] = beta[c];
    }
#pragma unroll
    for (int mf = 0; mf < 4; ++mf)
#pragma unroll
        for (int r = 0; r < 4; ++r) {
            float s = 0.f, s2 = 0.f;
#pragma unroll
            for (int nf = 0; nf < 4; ++nf) {
                float y = fmaxf(acc[mf][nf][r] + bcol[nf], 0.f);
                s += y; s2 += y * y;
            }
#pragma unroll
            for (int off = 8; off >= 1; off >>= 1) {
                s += __shfl_xor(s, off); s2 += __shfl_xor(s2, off);
            }
            if (p == 0) {
                int row = mf * 16 + q * 4 + r;
                part[(row * 4 + wid) * 2]     = s;
                part[(row * 4 + wid) * 2 + 1] = s2;
            }
        }
    __syncthreads();
    if (tid < 64) {
        float s = 0.f, s2 = 0.f;
#pragma unroll
        for (int w = 0; w < 4; ++w) {
            s  += part[(tid * 4 + w) * 2];
            s2 += part[(tid * 4 + w) * 2 + 1];
        }
        float m = s * (1.f / 256.f);
        float v = s2 * (1.f / 256.f) - m * m;
        tot[tid * 2]     = m;
        tot[tid * 2 + 1] = rsqrtf(v + 1e-5f);
    }
    __syncthreads();
#pragma unroll
    for (int mf = 0; mf < 4; ++mf)
#pragma unroll
        for (int r = 0; r < 4; ++r) {
            int row = mf * 16 + q * 4 + r;
            float m  = tot[row * 2];
            float rs = tot[row * 2 + 1];
            size_t gb = ((size_t)bb * TP_ + 1 + t0 + row) * D_;
#pragma unroll
            for (int nf = 0; nf < 4; ++nf) {
                int c = wid * 64 + nf * 16 + p;
                float y = fmaxf(acc[mf][nf][r] + bcol[nf], 0.f);
                dst[gb + c] = (__bf16)((y - m) * rs * gcol[nf] + becol[nf]);
            }
        }
}

// ------------- conv2: GEMM + fused LN + (h@wl+bl) -> pred only -------------
__global__ __launch_bounds__(256) void gemm2_pred_kernel(
    const __bf16* __restrict__ h1pad,  // (B, 514, 256)
    const __bf16* __restrict__ bmat,
    const float* __restrict__ bias,
    const float* __restrict__ gamma,
    const float* __restrict__ beta,
    const float* __restrict__ wl,
    const float* __restrict__ bl,
    float* __restrict__ pred)          // (B, T)
{
    __shared__ __align__(16) unsigned char ring[3 * BUFSZ];
    __shared__ float part[64 * 4 * 4];
    __shared__ float sg[2];
    {   // Sgw = sum g*wl, Sbw = sum be*wl + bl  (wave 0, before the pipeline)
        int ltid = threadIdx.x;
        if (ltid < 64) {
            f32x4 g  = *(const f32x4*)(gamma + 4 * ltid);
            f32x4 be = *(const f32x4*)(beta  + 4 * ltid);
            f32x4 w  = *(const f32x4*)(wl    + 4 * ltid);
            float a = g[0]*w[0] + g[1]*w[1] + g[2]*w[2] + g[3]*w[3];
            float b = be[0]*w[0] + be[1]*w[1] + be[2]*w[2] + be[3]*w[3];
#pragma unroll
            for (int off = 32; off >= 1; off >>= 1) {
                a += __shfl_xor(a, off); b += __shfl_xor(b, off);
            }
            if (ltid == 0) { sg[0] = a; sg[1] = b + bl[0]; }
        }
    }
    GEMM_CORE(h1pad)

    float bcol[4], gwcol[4];
#pragma unroll
    for (int nf = 0; nf < 4; ++nf) {
        int c = wid * 64 + nf * 16 + p;
        bcol[nf]  = bias[c];
        gwcol[nf] = gamma[c] * wl[c];
    }
#pragma unroll
    for (int mf = 0; mf < 4; ++mf)
#pragma unroll
        for (int r = 0; r < 4; ++r) {
            float s = 0.f, s2 = 0.f, s3 = 0.f;
#pragma unroll
            for (int nf = 0; nf < 4; ++nf) {
                float y = fmaxf(acc[mf][nf][r] + bcol[nf], 0.f);
                s += y; s2 += y * y; s3 += y * gwcol[nf];
            }
#pragma unroll
            for (int off = 8; off >= 1; off >>= 1) {
                s  += __shfl_xor(s, off);
                s2 += __shfl_xor(s2, off);
                s3 += __shfl_xor(s3, off);
            }
            if (p == 0) {
                int row = mf * 16 + q * 4 + r;
                part[(row * 4 + wid) * 4]     = s;
                part[(row * 4 + wid) * 4 + 1] = s2;
                part[(row * 4 + wid) * 4 + 2] = s3;
            }
        }
    __syncthreads();
    if (tid < 64) {
        float s = 0.f, s2 = 0.f, s3 = 0.f;
#pragma unroll
        for (int w = 0; w < 4; ++w) {
            s  += part[(tid * 4 + w) * 4];
            s2 += part[(tid * 4 + w) * 4 + 1];
            s3 += part[(tid * 4 + w) * 4 + 2];
        }
        float m  = s * (1.f / 256.f);
        float v  = s2 * (1.f / 256.f) - m * m;
        float rs = rsqrtf(v + 1e-5f);
        pred[bb * T_ + t0 + tid] = rs * (s3 - m * sg[0]) + sg[1];
    }
}

// Vectorized prep: xpad bf16 (8-wide), BmatT for both convs, h1pad zero rows.
__global__ __launch_bounds__(256) void prep_kernel(
    const float* __restrict__ x, const float* __restrict__ w1,
    const float* __restrict__ w2,
    __bf16* __restrict__ xpad, __bf16* __restrict__ bm1,
    __bf16* __restrict__ bm2, __bf16* __restrict__ h1pad)
{
    const int NX8 = B_ * TP_ * D_ / 8;      // 526,336
    const int NW8 = D_ * KTOT / 8;          // 24,576
    const int NZ8 = B_ * 2 * D_ / 8;        // 2,048
    const int total = NX8 + 2 * NW8 + NZ8;
    for (int i8 = blockIdx.x * blockDim.x + threadIdx.x; i8 < total;
         i8 += gridDim.x * blockDim.x) {
        if (i8 < NX8) {
            int e = i8 * 8;
            int b = e / (TP_ * D_);
            int rem = e - b * (TP_ * D_);
            int r = rem >> 8, d = rem & 255;
            int t = r - 1;
            bf16x8 o;
            if ((unsigned)t < (unsigned)T_) {
                const float* xp = x + ((size_t)b * T_ + t) * D_ + d;
                f32x4 v0 = *(const f32x4*)xp;
                f32x4 v1 = *(const f32x4*)(xp + 4);
#pragma unroll
                for (int u = 0; u < 4; ++u) { o[u] = (__bf16)v0[u]; o[u+4] = (__bf16)v1[u]; }
            } else {
#pragma unroll
                for (int u = 0; u < 8; ++u) o[u] = (__bf16)0.f;
            }
            *(bf16x8*)(xpad + e) = o;
        } else if (i8 < NX8 + 2 * NW8) {
            int j = (i8 - NX8) * 8;
            const float* ws = w1;
            __bf16* bm = bm1;
            if (j >= D_ * KTOT) { j -= D_ * KTOT; ws = w2; bm = bm2; }
            int n = j / KTOT;
            int kap = j - n * KTOT;
            int k = kap >> 8, i = kap & 255;
            bf16x8 o;
#pragma unroll
            for (int u = 0; u < 8; ++u)
                o[u] = (__bf16)ws[(n * D_ + i + u) * 3 + k];
            *(bf16x8*)(bm + n * KTOT + kap) = o;
        } else {
            int j = (i8 - NX8 - 2 * NW8) * 8;
            int b = j >> 9, qq = (j >> 8) & 1, d = j & 255;
            bf16x8 o;
#pragma unroll
            for (int u = 0; u < 8; ++u) o[u] = (__bf16)0.f;
            *(bf16x8*)(h1pad + ((size_t)b * TP_ + (qq ? TP_ - 1 : 0)) * D_ + d) = o;
        }
    }
}

// Per-batch inclusive cumsum of durations (ALPHA=1.0 -> dur == target).
__global__ __launch_bounds__(512) void scan_kernel(
    const int* __restrict__ td, int* __restrict__ ends)
{
    __shared__ int s[T_];
    int b = blockIdx.x, t = threadIdx.x;
    s[t] = td[b * T_ + t];
    __syncthreads();
    for (int off = 1; off < T_; off <<= 1) {
        int add = (t >= off) ? s[t - off] : 0;
        __syncthreads();
        s[t] += add;
        __syncthreads();
    }
    ends[b * T_ + t] = s[t];
}

// out[b,m,:] = x[b, t(m), :] via binary search over ends; zeros past lens[b].
__global__ __launch_bounds__(256) void gather_kernel(
    const float* __restrict__ x, const int* __restrict__ ends,
    float* __restrict__ out, int maxLen)
{
    int tid = threadIdx.x, wd = tid >> 6, lane = tid & 63;
    int idx = blockIdx.x * 4 + wd;
    int b = idx / maxLen, m = idx % maxLen;
    if (b >= B_) return;
    const int* e = &ends[b * T_];
    float4 r = make_float4(0.f, 0.f, 0.f, 0.f);
    if (m < e[T_ - 1]) {
        int lo = 0, hi = T_ - 1;   // first t with ends[t] > m
        while (lo < hi) {
            int mid = (lo + hi) >> 1;
            if (e[mid] > m) hi = mid; else lo = mid + 1;
        }
        r = *(const float4*)(&x[((size_t)b * T_ + lo) * D_ + 4 * lane]);
    }
    *(float4*)(&out[((size_t)b * maxLen + m) * D_ + 4 * lane]) = r;
}

extern "C" void kernel_launch(void* const* d_in, const int* in_sizes, int n_in,
                              void* d_out, int out_size, void* d_ws, size_t ws_size,
                              hipStream_t stream) {
    const float* x   = (const float*)d_in[0];
    const int*   td  = (const int*)d_in[1];
    const float* w1  = (const float*)d_in[2];
    const float* b1  = (const float*)d_in[3];
    const float* g1  = (const float*)d_in[4];
    const float* be1 = (const float*)d_in[5];
    const float* w2  = (const float*)d_in[6];
    const float* b2  = (const float*)d_in[7];
    const float* g2  = (const float*)d_in[8];
    const float* be2 = (const float*)d_in[9];
    const float* wl  = (const float*)d_in[10];
    const float* bl  = (const float*)d_in[11];
    float* outp = (float*)d_out;

    const int BT = B_ * T_;
    const int maxLen = (out_size - BT) / (B_ * D_);
    float* predp = outp + (size_t)B_ * maxLen * D_;

    const size_t SZ_XPAD = (size_t)B_ * TP_ * D_ * 2;
    const size_t SZ_H1   = SZ_XPAD;
    const size_t SZ_BM   = (size_t)D_ * KTOT * 2;
    const size_t SZ_ENDS = 65536;
    const size_t need = SZ_ENDS + SZ_XPAD + SZ_H1 + 2 * SZ_BM;

    int* endsp = (int*)d_ws;
    char* base;
    if (ws_size >= need) base = (char*)d_ws + SZ_ENDS;
    else                 base = (char*)d_out;   // consumed before gather overwrites

    __bf16* xpadp  = (__bf16*)(base);
    __bf16* h1padp = (__bf16*)(base + SZ_XPAD);
    __bf16* bm1p   = (__bf16*)(base + SZ_XPAD + SZ_H1);
    __bf16* bm2p   = (__bf16*)(base + SZ_XPAD + SZ_H1 + SZ_BM);

    prep_kernel<<<1024, 256, 0, stream>>>(x, w1, w2, xpadp, bm1p, bm2p, h1padp);
    gemm1_ln_kernel<<<BT / TILE_M, 256, 0, stream>>>(xpadp, bm1p, b1, g1, be1, h1padp);
    gemm2_pred_kernel<<<BT / TILE_M, 256, 0, stream>>>(h1padp, bm2p, b2, g2, be2, wl, bl, predp);
    scan_kernel<<<B_, T_, 0, stream>>>(td, endsp);
    gather_kernel<<<(B_ * maxLen + 3) / 4, 256, 0, stream>>>(x, endsp, outp, maxLen);
}

// Round 5
// 77.421 us; speedup vs baseline: 1.5374x; 1.0264x over previous
//
#include <hip/hip_runtime.h>
#include <math.h>

#define B_ 32
#define T_ 512
#define D_ 256
#define TP_ 514              // padded T for h1: one zero row each side
#define KTOT 768             // 3 taps x 256 channels
#define NSTEP 24             // KTOT / 32
#define TILE_M 64

typedef __bf16 bf16x8 __attribute__((ext_vector_type(8)));
typedef float  f32x4  __attribute__((ext_vector_type(4)));

__device__ __forceinline__ void gload16(const void* g, void* l) {
    __builtin_amdgcn_global_load_lds(
        (const __attribute__((address_space(1))) unsigned int*)g,
        (__attribute__((address_space(3))) unsigned int*)l, 16, 0, 0);
}

// Ring-3 LDS pipeline, 2 stages in flight, counted vmcnt (T3/T4).
// NLOAD = global_load_lds per thread per stage (uniform across threads).
#define PIPE_BODY(T, CBUF, SBUF, DOSTAGE, LAST, NLOAD)                  \
    do {                                                                \
        if (LAST) asm volatile("s_waitcnt vmcnt(0)" ::: "memory");      \
        else      asm volatile("s_waitcnt vmcnt(" #NLOAD ")" ::: "memory"); \
        __builtin_amdgcn_s_barrier();                                   \
        if (DOSTAGE) STAGE((T) + 2, SBUF);                              \
        COMPUTE(CBUF);                                                  \
    } while (0)

#define RUN_PIPE(NLOAD)                                                 \
    STAGE(0, 0); STAGE(1, 1);                                           \
    for (int t2 = 0; t2 < 7; ++t2) {                                    \
        int t = 3 * t2;                                                 \
        PIPE_BODY(t,     0, 2, true, false, NLOAD);                     \
        PIPE_BODY(t + 1, 1, 0, true, false, NLOAD);                     \
        PIPE_BODY(t + 2, 2, 1, true, false, NLOAD);                     \
    }                                                                   \
    PIPE_BODY(21, 0, 2, true,  false, NLOAD);                           \
    PIPE_BODY(22, 1, 0, false, false, NLOAD);                           \
    PIPE_BODY(23, 2, 1, false, true,  NLOAD);

// ---------------------------------------------------------------------------
// conv1: A = fp32 x staged directly to LDS (f32), converted to bf16 fragments
// in-register.  Per stage: A 64 rows x 32 f32 (8KB, 2 chunks/thread) +
// B 256 rows x 32 bf16 (16KB, 4 chunks/thread) = 6 gloads -> vmcnt(6).
// A chunk swizzle: slot = (ch/4) ^ (row&7) within the 128B row (involution
// applied to the gload SOURCE and the ds_read address).  OOB tap rows read
// from a 128B zero scratch.  Epilogue: bias/ReLU/LayerNorm -> bf16 h1pad.
// ---------------------------------------------------------------------------
#define BUFSZ1 24576   // A 8KB + B 16KB

__global__ __launch_bounds__(256) void gemm1_ln_kernel(
    const float* __restrict__ x,       // (B,512,256) fp32
    const __bf16* __restrict__ bmat,   // (256,768)
    const float* __restrict__ zsc,     // 128B zeros
    const float* __restrict__ bias,
    const float* __restrict__ gamma,
    const float* __restrict__ beta,
    __bf16* __restrict__ dst)          // h1pad (B,514,256)
{
    __shared__ __align__(16) unsigned char ring[3 * BUFSZ1];
    __shared__ float part[64 * 4 * 2];
    __shared__ float tot[64 * 2];
    const int tid = threadIdx.x, lane = tid & 63, wid = tid >> 6;
    const int p = lane & 15, q = lane >> 4;
    const int m0 = blockIdx.x * TILE_M;
    const int bb = m0 >> 9, t0 = m0 & 511;
    const float* xb = x + (size_t)bb * T_ * D_;

    // A-chunk assignment: chunks {tid, tid+256} of 512 (row = c>>3, slot = c&7)
    const int r0 = tid >> 3,        r1 = (tid + 256) >> 3;
    const int sub0 = (tid & 7) ^ (r0 & 7), sub1 = (tid & 7) ^ (r1 & 7);
    const int srow0 = t0 - 1 + r0,  srow1 = t0 - 1 + r1;

    f32x4 acc[4][4];
#pragma unroll
    for (int mf = 0; mf < 4; ++mf)
#pragma unroll
        for (int nf = 0; nf < 4; ++nf)
            acc[mf][nf] = (f32x4){0.f, 0.f, 0.f, 0.f};

    auto STAGE = [&](int kstep, int buf) {
        unsigned char* Ab = ring + buf * BUFSZ1;
        const int k = kstep >> 3, i0 = (kstep & 7) * 32;
        {
            int t = srow0 + k;
            const float* s = ((unsigned)t < (unsigned)T_)
                ? xb + (size_t)t * D_ + i0 + sub0 * 4 : zsc + sub0 * 4;
            gload16(s, Ab + tid * 16);
        }
        {
            int t = srow1 + k;
            const float* s = ((unsigned)t < (unsigned)T_)
                ? xb + (size_t)t * D_ + i0 + sub1 * 4 : zsc + sub1 * 4;
            gload16(s, Ab + (tid + 256) * 16);
        }
#pragma unroll
        for (int pp = 0; pp < 4; ++pp) {   // B: 256 rows x 32 bf16
            int c = pp * 256 + tid;
            int n = c >> 2, cb = c & 3, scb = cb ^ (n & 3);
            gload16(bmat + (size_t)n * KTOT + kstep * 32 + scb * 8,
                    Ab + 8192 + c * 16);
        }
    };
    auto COMPUTE = [&](int buf) {
        unsigned char* Ab = ring + buf * BUFSZ1;
        unsigned char* Bb = Ab + 8192;
        const int rA = lane & 15;
        const int swzB = (q ^ (rA & 3)) * 16;
        bf16x8 a[4], bv[4];
#pragma unroll
        for (int mf = 0; mf < 4; ++mf) {
            const unsigned char* ap = Ab + (mf * 16 + rA) * 128;
            f32x4 lo = *(const f32x4*)(ap + (((q * 2)     ^ (rA & 7)) * 16));
            f32x4 hi = *(const f32x4*)(ap + (((q * 2 + 1) ^ (rA & 7)) * 16));
#pragma unroll
            for (int e = 0; e < 4; ++e) {
                a[mf][e]     = (__bf16)lo[e];
                a[mf][e + 4] = (__bf16)hi[e];
            }
        }
#pragma unroll
        for (int nf = 0; nf < 4; ++nf)
            bv[nf] = *(const bf16x8*)(Bb + (wid * 64 + nf * 16 + rA) * 64 + swzB);
#pragma unroll
        for (int mf = 0; mf < 4; ++mf)
#pragma unroll
            for (int nf = 0; nf < 4; ++nf)
                acc[mf][nf] = __builtin_amdgcn_mfma_f32_16x16x32_bf16(
                    a[mf], bv[nf], acc[mf][nf], 0, 0, 0);
    };

    RUN_PIPE(6)

    // ---- epilogue: bias+ReLU -> cross-wave LN -> bf16 h1pad ----
    float bcol[4], gcol[4], becol[4];
#pragma unroll
    for (int nf = 0; nf < 4; ++nf) {
        int c = wid * 64 + nf * 16 + p;
        bcol[nf] = bias[c]; gcol[nf] = gamma[c]; becol[nf] = beta[c];
    }
#pragma unroll
    for (int mf = 0; mf < 4; ++mf)
#pragma unroll
        for (int r = 0; r < 4; ++r) {
            float s = 0.f, s2 = 0.f;
#pragma unroll
            for (int nf = 0; nf < 4; ++nf) {
                float y = fmaxf(acc[mf][nf][r] + bcol[nf], 0.f);
                s += y; s2 += y * y;
            }
#pragma unroll
            for (int off = 8; off >= 1; off >>= 1) {
                s += __shfl_xor(s, off); s2 += __shfl_xor(s2, off);
            }
            if (p == 0) {
                int row = mf * 16 + q * 4 + r;
                part[(row * 4 + wid) * 2]     = s;
                part[(row * 4 + wid) * 2 + 1] = s2;
            }
        }
    __syncthreads();
    if (tid < 64) {
        float s = 0.f, s2 = 0.f;
#pragma unroll
        for (int w = 0; w < 4; ++w) {
            s  += part[(tid * 4 + w) * 2];
            s2 += part[(tid * 4 + w) * 2 + 1];
        }
        float m = s * (1.f / 256.f);
        float v = s2 * (1.f / 256.f) - m * m;
        tot[tid * 2]     = m;
        tot[tid * 2 + 1] = rsqrtf(v + 1e-5f);
    }
    __syncthreads();
#pragma unroll
    for (int mf = 0; mf < 4; ++mf)
#pragma unroll
        for (int r = 0; r < 4; ++r) {
            int row = mf * 16 + q * 4 + r;
            float m  = tot[row * 2];
            float rs = tot[row * 2 + 1];
            size_t gb = ((size_t)bb * TP_ + 1 + t0 + row) * D_;
#pragma unroll
            for (int nf = 0; nf < 4; ++nf) {
                int c = wid * 64 + nf * 16 + p;
                float y = fmaxf(acc[mf][nf][r] + bcol[nf], 0.f);
                dst[gb + c] = (__bf16)((y - m) * rs * gcol[nf] + becol[nf]);
            }
        }
}

// ---------------------------------------------------------------------------
// conv2: bf16 A (h1pad) staging as in round 4 (5 gloads -> vmcnt(5)),
// epilogue folds LN + (h@wl+bl):  pred = rstd*(S3 - mean*Sgw) + Sbw.
// ---------------------------------------------------------------------------
#define BUFSZ2 20480   // A 4KB + B 16KB

__global__ __launch_bounds__(256) void gemm2_pred_kernel(
    const __bf16* __restrict__ h1pad,  // (B, 514, 256)
    const __bf16* __restrict__ bmat,
    const float* __restrict__ bias,
    const float* __restrict__ gamma,
    const float* __restrict__ beta,
    const float* __restrict__ wl,
    const float* __restrict__ bl,
    float* __restrict__ pred)          // (B, T)
{
    __shared__ __align__(16) unsigned char ring[3 * BUFSZ2];
    __shared__ float part[64 * 4 * 4];
    __shared__ float sg[2];
    const int tid = threadIdx.x, lane = tid & 63, wid = tid >> 6;
    const int p = lane & 15, q = lane >> 4;
    const int m0 = blockIdx.x * TILE_M;
    const int bb = m0 >> 9, t0 = m0 & 511;
    if (tid < 64) {   // Sgw = sum g*wl, Sbw = sum be*wl + bl
        f32x4 g  = *(const f32x4*)(gamma + 4 * tid);
        f32x4 be = *(const f32x4*)(beta  + 4 * tid);
        f32x4 w  = *(const f32x4*)(wl    + 4 * tid);
        float a = g[0]*w[0] + g[1]*w[1] + g[2]*w[2] + g[3]*w[3];
        float b = be[0]*w[0] + be[1]*w[1] + be[2]*w[2] + be[3]*w[3];
#pragma unroll
        for (int off = 32; off >= 1; off >>= 1) {
            a += __shfl_xor(a, off); b += __shfl_xor(b, off);
        }
        if (tid == 0) { sg[0] = a; sg[1] = b + bl[0]; }
    }
    const __bf16* aBase = h1pad + ((size_t)bb * TP_ + t0) * D_;

    f32x4 acc[4][4];
#pragma unroll
    for (int mf = 0; mf < 4; ++mf)
#pragma unroll
        for (int nf = 0; nf < 4; ++nf)
            acc[mf][nf] = (f32x4){0.f, 0.f, 0.f, 0.f};

    auto STAGE = [&](int kstep, int buf) {
        unsigned char* Ab = ring + buf * BUFSZ2;
        {   // A: 64 rows x 32 bf16
            int r = tid >> 2, cb = tid & 3, scb = cb ^ (r & 3);
            int k = kstep >> 3, i0 = (kstep & 7) * 32;
            gload16(aBase + (size_t)(r + k) * D_ + i0 + scb * 8, Ab + tid * 16);
        }
#pragma unroll
        for (int pp = 0; pp < 4; ++pp) {  // B: 256 rows x 32 bf16
            int c = pp * 256 + tid;
            int n = c >> 2, cb = c & 3, scb = cb ^ (n & 3);
            gload16(bmat + (size_t)n * KTOT + kstep * 32 + scb * 8,
                    Ab + 4096 + c * 16);
        }
    };
    auto COMPUTE = [&](int buf) {
        unsigned char* Ab = ring + buf * BUFSZ2;
        unsigned char* Bb = Ab + 4096;
        const int rA = lane & 15;
        const int swz = (q ^ (rA & 3)) * 16;
        bf16x8 a[4], bv[4];
#pragma unroll
        for (int mf = 0; mf < 4; ++mf)
            a[mf] = *(const bf16x8*)(Ab + (mf * 16 + rA) * 64 + swz);
#pragma unroll
        for (int nf = 0; nf < 4; ++nf)
            bv[nf] = *(const bf16x8*)(Bb + (wid * 64 + nf * 16 + rA) * 64 + swz);
#pragma unroll
        for (int mf = 0; mf < 4; ++mf)
#pragma unroll
            for (int nf = 0; nf < 4; ++nf)
                acc[mf][nf] = __builtin_amdgcn_mfma_f32_16x16x32_bf16(
                    a[mf], bv[nf], acc[mf][nf], 0, 0, 0);
    };

    RUN_PIPE(5)

    float bcol[4], gwcol[4];
#pragma unroll
    for (int nf = 0; nf < 4; ++nf) {
        int c = wid * 64 + nf * 16 + p;
        bcol[nf]  = bias[c];
        gwcol[nf] = gamma[c] * wl[c];
    }
#pragma unroll
    for (int mf = 0; mf < 4; ++mf)
#pragma unroll
        for (int r = 0; r < 4; ++r) {
            float s = 0.f, s2 = 0.f, s3 = 0.f;
#pragma unroll
            for (int nf = 0; nf < 4; ++nf) {
                float y = fmaxf(acc[mf][nf][r] + bcol[nf], 0.f);
                s += y; s2 += y * y; s3 += y * gwcol[nf];
            }
#pragma unroll
            for (int off = 8; off >= 1; off >>= 1) {
                s  += __shfl_xor(s, off);
                s2 += __shfl_xor(s2, off);
                s3 += __shfl_xor(s3, off);
            }
            if (p == 0) {
                int row = mf * 16 + q * 4 + r;
                part[(row * 4 + wid) * 4]     = s;
                part[(row * 4 + wid) * 4 + 1] = s2;
                part[(row * 4 + wid) * 4 + 2] = s3;
            }
        }
    __syncthreads();
    if (tid < 64) {
        float s = 0.f, s2 = 0.f, s3 = 0.f;
#pragma unroll
        for (int w = 0; w < 4; ++w) {
            s  += part[(tid * 4 + w) * 4];
            s2 += part[(tid * 4 + w) * 4 + 1];
            s3 += part[(tid * 4 + w) * 4 + 2];
        }
        float m  = s * (1.f / 256.f);
        float v  = s2 * (1.f / 256.f) - m * m;
        float rs = rsqrtf(v + 1e-5f);
        pred[bb * T_ + t0 + tid] = rs * (s3 - m * sg[0]) + sg[1];
    }
}

// Small prep: scan (blocks 0..31) + weight transpose + h1pad pad rows + zsc.
__global__ __launch_bounds__(512) void prep_kernel(
    const int* __restrict__ td, const float* __restrict__ w1,
    const float* __restrict__ w2,
    int* __restrict__ ends, float* __restrict__ zsc,
    __bf16* __restrict__ bm1, __bf16* __restrict__ bm2,
    __bf16* __restrict__ h1pad)
{
    if (blockIdx.x < 32) {   // inclusive cumsum per batch
        __shared__ int s[T_];
        int b = blockIdx.x, t = threadIdx.x;
        s[t] = td[b * T_ + t];
        __syncthreads();
        for (int off = 1; off < T_; off <<= 1) {
            int add = (t >= off) ? s[t - off] : 0;
            __syncthreads();
            s[t] += add;
            __syncthreads();
        }
        ends[b * T_ + t] = s[t];
        return;
    }
    const int NW8 = D_ * KTOT / 8;       // 24576 per conv
    const int NZ8 = B_ * 2 * D_ / 8;     // 2048
    int idx = (blockIdx.x - 32) * 512 + threadIdx.x;
    if (idx < 2 * NW8) {
        int j = idx * 8;
        const float* ws = w1;
        __bf16* bm = bm1;
        if (j >= D_ * KTOT) { j -= D_ * KTOT; ws = w2; bm = bm2; }
        int n = j / KTOT;
        int kap = j - n * KTOT;
        int k = kap >> 8, i = kap & 255;
        bf16x8 o;
#pragma unroll
        for (int u = 0; u < 8; ++u)
            o[u] = (__bf16)ws[(n * D_ + i + u) * 3 + k];
        *(bf16x8*)(bm + n * KTOT + kap) = o;
    } else if (idx < 2 * NW8 + NZ8) {
        int j = (idx - 2 * NW8) * 8;
        int b = j >> 9, qq = (j >> 8) & 1, d = j & 255;
        bf16x8 o;
#pragma unroll
        for (int u = 0; u < 8; ++u) o[u] = (__bf16)0.f;
        *(bf16x8*)(h1pad + ((size_t)b * TP_ + (qq ? TP_ - 1 : 0)) * D_ + d) = o;
    } else if (idx < 2 * NW8 + NZ8 + 8) {
        int j = idx - 2 * NW8 - NZ8;
        *(f32x4*)(zsc + 4 * j) = (f32x4){0.f, 0.f, 0.f, 0.f};
    }
}

// out[b,m,:] = x[b, t(m), :] via binary search over ends; zeros past lens[b].
__global__ __launch_bounds__(256) void gather_kernel(
    const float* __restrict__ x, const int* __restrict__ ends,
    float* __restrict__ out, int maxLen)
{
    int tid = threadIdx.x, wd = tid >> 6, lane = tid & 63;
    int idx = blockIdx.x * 4 + wd;
    int b = idx / maxLen, m = idx % maxLen;
    if (b >= B_) return;
    const int* e = &ends[b * T_];
    float4 r = make_float4(0.f, 0.f, 0.f, 0.f);
    if (m < e[T_ - 1]) {
        int lo = 0, hi = T_ - 1;   // first t with ends[t] > m
        while (lo < hi) {
            int mid = (lo + hi) >> 1;
            if (e[mid] > m) hi = mid; else lo = mid + 1;
        }
        r = *(const float4*)(&x[((size_t)b * T_ + lo) * D_ + 4 * lane]);
    }
    *(float4*)(&out[((size_t)b * maxLen + m) * D_ + 4 * lane]) = r;
}

extern "C" void kernel_launch(void* const* d_in, const int* in_sizes, int n_in,
                              void* d_out, int out_size, void* d_ws, size_t ws_size,
                              hipStream_t stream) {
    const float* x   = (const float*)d_in[0];
    const int*   td  = (const int*)d_in[1];
    const float* w1  = (const float*)d_in[2];
    const float* b1  = (const float*)d_in[3];
    const float* g1  = (const float*)d_in[4];
    const float* be1 = (const float*)d_in[5];
    const float* w2  = (const float*)d_in[6];
    const float* b2  = (const float*)d_in[7];
    const float* g2  = (const float*)d_in[8];
    const float* be2 = (const float*)d_in[9];
    const float* wl  = (const float*)d_in[10];
    const float* bl  = (const float*)d_in[11];
    float* outp = (float*)d_out;

    const int BT = B_ * T_;
    const int maxLen = (out_size - BT) / (B_ * D_);
    float* predp = outp + (size_t)B_ * maxLen * D_;

    const size_t SZ_ENDS = 65536;
    const size_t SZ_ZSC  = 1024;
    const size_t SZ_H1   = (size_t)B_ * TP_ * D_ * 2;   // 8,421,376
    const size_t SZ_BM   = (size_t)D_ * KTOT * 2;       // 393,216
    const size_t need = SZ_ENDS + SZ_ZSC + SZ_H1 + 2 * SZ_BM;

    int*   endsp = (int*)d_ws;                           // always in ws (tiny)
    float* zscp  = (float*)((char*)d_ws + SZ_ENDS);
    char* base;
    if (ws_size >= need) base = (char*)d_ws + SZ_ENDS + SZ_ZSC;
    else                 base = (char*)d_out;  // consumed before gather overwrites

    __bf16* h1padp = (__bf16*)(base);
    __bf16* bm1p   = (__bf16*)(base + SZ_H1);
    __bf16* bm2p   = (__bf16*)(base + SZ_H1 + SZ_BM);

    prep_kernel<<<32 + 100, 512, 0, stream>>>(td, w1, w2, endsp, zscp,
                                              bm1p, bm2p, h1padp);
    gemm1_ln_kernel<<<BT / TILE_M, 256, 0, stream>>>(x, bm1p, zscp,
                                                     b1, g1, be1, h1padp);
    gemm2_pred_kernel<<<BT / TILE_M, 256, 0, stream>>>(h1padp, bm2p, b2, g2, be2,
                                                       wl, bl, predp);
    gather_kernel<<<(B_ * maxLen + 3) / 4, 256, 0, stream>>>(x, endsp, outp, maxLen);
}